// Round 2
// baseline (102.917 us; speedup 1.0000x reference)
//
#include <hip/hip_runtime.h>

typedef float f32x4 __attribute__((ext_vector_type(4)));
typedef __bf16 bf16x8 __attribute__((ext_vector_type(8)));

#define BN_EPS 1e-5f

__device__ __forceinline__ unsigned short f2bf(float x) {
  union { float f; unsigned u; } v; v.f = x;
  unsigned r = v.u + 0x7fffu + ((v.u >> 16) & 1u);
  return (unsigned short)(r >> 16);
}

// ---------------- prep: fold BN into weights (bf16) + biases (fp32) ----------------
__global__ void prep_kernel(const float* __restrict__ W1, const float* __restrict__ b1,
                            const float* __restrict__ g1, const float* __restrict__ bt1,
                            const float* __restrict__ mu1, const float* __restrict__ v1,
                            const float* __restrict__ W2, const float* __restrict__ b2,
                            const float* __restrict__ g2, const float* __restrict__ bt2,
                            const float* __restrict__ mu2, const float* __restrict__ v2,
                            unsigned short* __restrict__ W1b, unsigned short* __restrict__ W2b,
                            float* __restrict__ bias1, float* __restrict__ bias2) {
  int tid = blockIdx.x * 256 + threadIdx.x;
  if (tid < 98304) {                       // W1: 256 x 384
    int o = tid / 384;
    float s = g1[o] * rsqrtf(v1[o] + BN_EPS);
    W1b[tid] = f2bf(W1[tid] * s);
    if (tid < 256) bias1[tid] = (b1[tid] - mu1[tid]) * (g1[tid] * rsqrtf(v1[tid] + BN_EPS)) + bt1[tid];
  } else if (tid < 98304 + 32768) {        // W2: 128 x 256
    int t = tid - 98304;
    int o = t / 256;
    float s = g2[o] * rsqrtf(v2[o] + BN_EPS);
    W2b[t] = f2bf(W2[t] * s);
    if (t < 128) bias2[t] = (b2[t] - mu2[t]) * (g2[t] * rsqrtf(v2[t] + BN_EPS)) + bt2[t];
  }
}

// ---------------- kernel A: 3-NN ----------------
// 64 points/block (1024 blocks), 256 threads.
// Thread (q = tid>>5, u = tid&31): candidates [128q,128q+128) for points 2u, 2u+1.
// Output per point: float4{w0,w1,w2, bits(j0 | j1<<10 | j2<<20)}.
__global__ __launch_bounds__(256, 4)
void nn3_kernel(const float* __restrict__ unknown, const float* __restrict__ known,
                float4* __restrict__ wi4) {
  __shared__ float4 kxyz[1024];            // 16 KB (xyz + pad)
  __shared__ float sd[64 * 25];            // 24 entries + 1 pad per point
  __shared__ int   si[64 * 25];

  int bid = blockIdx.x;
  int swz = ((bid & 7) << 7) | (bid >> 3); // XCD-contiguous remap, bijective for 1024
  int b   = swz >> 6;
  int i0  = (swz & 63) << 6;

  int tid = threadIdx.x;

  // stage known xyz into float4-padded LDS
  float* kf = (float*)kxyz;
  for (int t = tid; t < 3072; t += 256) {
    int r = t / 3, c = t - r * 3;
    kf[r * 4 + c] = known[b * 3072 + t];
  }

  int u = tid & 31;
  int q = tid >> 5;
  int p0 = i0 + u * 2;
  const float* up = unknown + ((size_t)b * 4096 + p0) * 3;
  float ax = up[0], ay = up[1], az = up[2];
  float bx = up[3], by = up[4], bz = up[5];
  __syncthreads();

  float a0 = 3e38f, a1 = 3e38f, a2 = 3e38f;
  float e0 = 3e38f, e1 = 3e38f, e2 = 3e38f;
  int aj0 = 0, aj1 = 0, aj2 = 0, ej0 = 0, ej1 = 0, ej2 = 0;
  int jb = q << 7;
  #pragma unroll 4
  for (int jj = 0; jj < 128; ++jj) {
    int j = jb + jj;
    float4 k = kxyz[j];
    {
      float dx = ax - k.x, dy = ay - k.y, dz = az - k.z;
      float d = dx * dx + dy * dy + dz * dz;
      bool c0 = d < a0, c1 = d < a1, c2 = d < a2;
      aj2 = c1 ? aj1 : (c2 ? j : aj2);
      aj1 = c0 ? aj0 : (c1 ? j : aj1);
      aj0 = c0 ? j : aj0;
      float na2 = __builtin_amdgcn_fmed3f(a1, a2, d);   // uses old a1,a2
      float na1 = __builtin_amdgcn_fmed3f(a0, a1, d);   // uses old a0,a1
      a0 = fminf(a0, d); a1 = na1; a2 = na2;
    }
    {
      float dx = bx - k.x, dy = by - k.y, dz = bz - k.z;
      float d = dx * dx + dy * dy + dz * dz;
      bool c0 = d < e0, c1 = d < e1, c2 = d < e2;
      ej2 = c1 ? ej1 : (c2 ? j : ej2);
      ej1 = c0 ? ej0 : (c1 ? j : ej1);
      ej0 = c0 ? j : ej0;
      float na2 = __builtin_amdgcn_fmed3f(e1, e2, d);
      float na1 = __builtin_amdgcn_fmed3f(e0, e1, d);
      e0 = fminf(e0, d); e1 = na1; e2 = na2;
    }
  }
  {
    int base = (u * 2) * 25 + q * 3;
    sd[base] = a0; sd[base + 1] = a1; sd[base + 2] = a2;
    si[base] = aj0; si[base + 1] = aj1; si[base + 2] = aj2;
    base += 25;
    sd[base] = e0; sd[base + 1] = e1; sd[base + 2] = e2;
    si[base] = ej0; si[base + 1] = ej1; si[base + 2] = ej2;
  }
  __syncthreads();

  // merge 8 chunk-partials per point (chunk-major order keeps lowest-index-on-tie)
  if (tid < 64) {
    float m0 = 3e38f, m1 = 3e38f, m2 = 3e38f;
    int n0 = 0, n1 = 0, n2 = 0;
    int base = tid * 25;
    for (int e = 0; e < 24; ++e) {
      float d = sd[base + e]; int j = si[base + e];
      bool c0 = d < m0, c1 = d < m1, c2 = d < m2;
      n2 = c1 ? n1 : (c2 ? j : n2);
      n1 = c0 ? n0 : (c1 ? j : n1);
      n0 = c0 ? j : n0;
      float t2 = __builtin_amdgcn_fmed3f(m1, m2, d);
      float t1 = __builtin_amdgcn_fmed3f(m0, m1, d);
      m0 = fminf(m0, d); m1 = t1; m2 = t2;
    }
    float r0 = 1.0f / (m0 + 1e-10f);
    float r1 = 1.0f / (m1 + 1e-10f);
    float r2 = 1.0f / (m2 + 1e-10f);
    float rs = 1.0f / (r0 + r1 + r2);
    float4 o;
    o.x = r0 * rs; o.y = r1 * rs; o.z = r2 * rs;
    o.w = __int_as_float(n0 | (n1 << 10) | (n2 << 20));
    wi4[(size_t)b * 4096 + i0 + tid] = o;
  }
}

// ---------------- kernel B: interpolate + concat + MLP(2 layers) ----------------
// 64 points per block (1024 blocks), 256 threads (4 waves).
__global__ __launch_bounds__(256, 3)
void mlp_kernel(const float4* __restrict__ wi4,
                const float* __restrict__ unknow_feats, const float* __restrict__ known_feats,
                const unsigned short* __restrict__ W1b, const unsigned short* __restrict__ W2b,
                const float* __restrict__ bias1, const float* __restrict__ bias2,
                float* __restrict__ out) {
  __shared__ float w_s[64 * 3];
  __shared__ int   i_s[64 * 3];
  __shared__ __align__(16) unsigned char xbuf[64 * 768];  // x tile / y tile / f32 out tile

  int bid = blockIdx.x;
  int swz = ((bid & 7) << 7) | (bid >> 3);
  int b   = swz >> 6;
  int i0  = (swz & 63) << 6;

  int tid = threadIdx.x;
  int l = tid & 63;
  int q = tid >> 6;

  if (tid < 64) {
    float4 v = wi4[(size_t)b * 4096 + i0 + tid];
    w_s[tid * 3 + 0] = v.x; w_s[tid * 3 + 1] = v.y; w_s[tid * 3 + 2] = v.z;
    int pk = __float_as_int(v.w);
    i_s[tid * 3 + 0] = pk & 1023;
    i_s[tid * 3 + 1] = (pk >> 10) & 1023;
    i_s[tid * 3 + 2] = (pk >> 20) & 1023;
  }
  __syncthreads();

  // ---- interpolate -> x cols [0,256), bf16, XOR-swizzled LDS ----
  {
    int pp = tid >> 6;
    int cq = tid & 63;
    const float4* kf = (const float4*)(known_feats + (size_t)b * 1024 * 256);
    for (int po = 0; po < 16; ++po) {
      int p = po * 4 + pp;
      int ia = i_s[p * 3 + 0], ib = i_s[p * 3 + 1], ic = i_s[p * 3 + 2];
      float wa = w_s[p * 3 + 0], wb = w_s[p * 3 + 1], wc = w_s[p * 3 + 2];
      float4 va = kf[ia * 64 + cq];
      float4 vb = kf[ib * 64 + cq];
      float4 vc = kf[ic * 64 + cq];
      ushort4 h;
      h.x = f2bf(wa * va.x + wb * vb.x + wc * vc.x);
      h.y = f2bf(wa * va.y + wb * vb.y + wc * vc.y);
      h.z = f2bf(wa * va.z + wb * vb.z + wc * vc.z);
      h.w = f2bf(wa * va.w + wb * vb.w + wc * vc.w);
      int byte = p * 768 + cq * 8;
      byte ^= (p & 7) << 4;
      *(ushort4*)(xbuf + byte) = h;
    }
  }
  // ---- copy unknow_feats -> x cols [256,384) ----
  {
    int pp = tid >> 5;
    int cq = tid & 31;
    const float4* uf = (const float4*)(unknow_feats + ((size_t)b * 4096 + i0) * 128);
    for (int po = 0; po < 8; ++po) {
      int p = po * 8 + pp;
      float4 v = uf[p * 32 + cq];
      ushort4 h;
      h.x = f2bf(v.x); h.y = f2bf(v.y); h.z = f2bf(v.z); h.w = f2bf(v.w);
      int byte = p * 768 + 512 + cq * 8;
      byte ^= (p & 7) << 4;
      *(ushort4*)(xbuf + byte) = h;
    }
  }
  __syncthreads();

  // ---- GEMM1: (64x384) x (384->256), wave q owns cols [64q, 64q+64) ----
  int lr = l & 15;
  int lk = l >> 4;
  f32x4 acc[4][4];
  #pragma unroll
  for (int m = 0; m < 4; ++m)
    #pragma unroll
    for (int n = 0; n < 4; ++n) acc[m][n] = (f32x4){0.f, 0.f, 0.f, 0.f};

  __builtin_amdgcn_s_setprio(1);
  for (int kk = 0; kk < 12; ++kk) {
    int kb = kk * 32 + lk * 8;
    bf16x8 a[4];
    #pragma unroll
    for (int m = 0; m < 4; ++m) {
      int row = m * 16 + lr;
      int byte = row * 768 + kb * 2;
      byte ^= (row & 7) << 4;
      a[m] = *(const bf16x8*)(xbuf + byte);
    }
    #pragma unroll
    for (int n = 0; n < 4; ++n) {
      int wr = q * 64 + n * 16 + lr;
      bf16x8 bb = *(const bf16x8*)(W1b + wr * 384 + kb);
      #pragma unroll
      for (int m = 0; m < 4; ++m)
        acc[m][n] = __builtin_amdgcn_mfma_f32_16x16x32_bf16(a[m], bb, acc[m][n], 0, 0, 0);
    }
  }
  __builtin_amdgcn_s_setprio(0);

  float bs1[4];
  #pragma unroll
  for (int n = 0; n < 4; ++n) bs1[n] = bias1[q * 64 + n * 16 + lr];

  __syncthreads();   // xbuf reads done; overwrite with y tile
  #pragma unroll
  for (int m = 0; m < 4; ++m)
    #pragma unroll
    for (int n = 0; n < 4; ++n)
      #pragma unroll
      for (int i = 0; i < 4; ++i) {
        int r = m * 16 + lk * 4 + i;
        int c = q * 64 + n * 16 + lr;
        float val = fmaxf(acc[m][n][i] + bs1[n], 0.0f);
        int byte = r * 512 + c * 2;
        byte ^= (r & 7) << 4;
        *(unsigned short*)(xbuf + byte) = f2bf(val);
      }
  __syncthreads();

  // ---- GEMM2: (64x256) x (256->128), wave q owns cols [32q, 32q+32) ----
  f32x4 acc2[4][2];
  #pragma unroll
  for (int m = 0; m < 4; ++m)
    #pragma unroll
    for (int n = 0; n < 2; ++n) acc2[m][n] = (f32x4){0.f, 0.f, 0.f, 0.f};

  __builtin_amdgcn_s_setprio(1);
  for (int kk = 0; kk < 8; ++kk) {
    int kb = kk * 32 + lk * 8;
    bf16x8 a[4];
    #pragma unroll
    for (int m = 0; m < 4; ++m) {
      int row = m * 16 + lr;
      int byte = row * 512 + kb * 2;
      byte ^= (row & 7) << 4;
      a[m] = *(const bf16x8*)(xbuf + byte);
    }
    #pragma unroll
    for (int n = 0; n < 2; ++n) {
      int wr = q * 32 + n * 16 + lr;
      bf16x8 bb = *(const bf16x8*)(W2b + wr * 256 + kb);
      #pragma unroll
      for (int m = 0; m < 4; ++m)
        acc2[m][n] = __builtin_amdgcn_mfma_f32_16x16x32_bf16(a[m], bb, acc2[m][n], 0, 0, 0);
    }
  }
  __builtin_amdgcn_s_setprio(0);

  float bs2[2];
  #pragma unroll
  for (int n = 0; n < 2; ++n) bs2[n] = bias2[q * 32 + n * 16 + lr];

  // ---- epilogue: stage f32 out tile (stride 132) in LDS, then coalesced float4 stores ----
  __syncthreads();   // all xbuf (y tile) reads done
  float* ot = (float*)xbuf;
  #pragma unroll
  for (int m = 0; m < 4; ++m)
    #pragma unroll
    for (int n = 0; n < 2; ++n)
      #pragma unroll
      for (int i = 0; i < 4; ++i) {
        int r = m * 16 + lk * 4 + i;
        int c = q * 32 + n * 16 + lr;
        ot[r * 132 + c] = fmaxf(acc2[m][n][i] + bs2[n], 0.0f);
      }
  __syncthreads();
  {
    float4* out4 = (float4*)(out + ((size_t)b * 4096 + i0) * 128);
    for (int t = tid; t < 2048; t += 256) {
      int pr = t >> 5;
      int c4 = t & 31;
      float4 v = *(const float4*)(ot + pr * 132 + c4 * 4);
      out4[pr * 32 + c4] = v;
    }
  }
}

extern "C" void kernel_launch(void* const* d_in, const int* in_sizes, int n_in,
                              void* d_out, int out_size, void* d_ws, size_t ws_size,
                              hipStream_t stream) {
  const float* unknown      = (const float*)d_in[0];
  const float* known        = (const float*)d_in[1];
  const float* unknow_feats = (const float*)d_in[2];
  const float* known_feats  = (const float*)d_in[3];
  const float* W1  = (const float*)d_in[4];
  const float* b1  = (const float*)d_in[5];
  const float* g1  = (const float*)d_in[6];
  const float* bt1 = (const float*)d_in[7];
  const float* mu1 = (const float*)d_in[8];
  const float* v1  = (const float*)d_in[9];
  const float* W2  = (const float*)d_in[10];
  const float* b2  = (const float*)d_in[11];
  const float* g2  = (const float*)d_in[12];
  const float* bt2 = (const float*)d_in[13];
  const float* mu2 = (const float*)d_in[14];
  const float* v2  = (const float*)d_in[15];

  unsigned short* W1b = (unsigned short*)d_ws;       // 98304 bf16   (196608 B)
  unsigned short* W2b = W1b + 98304;                 // 32768 bf16   (65536 B)
  float* bias1 = (float*)(W2b + 32768);              // 256 f32
  float* bias2 = bias1 + 256;                        // 128 f32
  float4* wi4  = (float4*)((char*)d_ws + 263680);    // 65536 float4 (1 MB)

  prep_kernel<<<512, 256, 0, stream>>>(W1, b1, g1, bt1, mu1, v1,
                                       W2, b2, g2, bt2, mu2, v2,
                                       W1b, W2b, bias1, bias2);
  nn3_kernel<<<1024, 256, 0, stream>>>(unknown, known, wi4);
  mlp_kernel<<<1024, 256, 0, stream>>>(wi4, unknow_feats, known_feats,
                                       W1b, W2b, bias1, bias2, (float*)d_out);
}

// Round 3
// 81.869 us; speedup vs baseline: 1.2571x; 1.2571x over previous
//
#include <hip/hip_runtime.h>

typedef float f32x4 __attribute__((ext_vector_type(4)));
typedef __bf16 bf16x8 __attribute__((ext_vector_type(8)));

#define BN_EPS 1e-5f

__device__ __forceinline__ unsigned short f2bf(float x) {
  union { float f; unsigned u; } v; v.f = x;
  unsigned r = v.u + 0x7fffu + ((v.u >> 16) & 1u);
  return (unsigned short)(r >> 16);
}

// ---------------- prep: fold BN into weights (bf16) + biases (fp32) ----------------
__global__ void prep_kernel(const float* __restrict__ W1, const float* __restrict__ b1,
                            const float* __restrict__ g1, const float* __restrict__ bt1,
                            const float* __restrict__ mu1, const float* __restrict__ v1,
                            const float* __restrict__ W2, const float* __restrict__ b2,
                            const float* __restrict__ g2, const float* __restrict__ bt2,
                            const float* __restrict__ mu2, const float* __restrict__ v2,
                            unsigned short* __restrict__ W1b, unsigned short* __restrict__ W2b,
                            float* __restrict__ bias1, float* __restrict__ bias2) {
  int tid = blockIdx.x * 256 + threadIdx.x;
  if (tid < 98304) {                       // W1: 256 x 384
    int o = tid / 384;
    float s = g1[o] * rsqrtf(v1[o] + BN_EPS);
    W1b[tid] = f2bf(W1[tid] * s);
    if (tid < 256) bias1[tid] = (b1[tid] - mu1[tid]) * (g1[tid] * rsqrtf(v1[tid] + BN_EPS)) + bt1[tid];
  } else if (tid < 98304 + 32768) {        // W2: 128 x 256
    int t = tid - 98304;
    int o = t / 256;
    float s = g2[o] * rsqrtf(v2[o] + BN_EPS);
    W2b[t] = f2bf(W2[t] * s);
    if (t < 128) bias2[t] = (b2[t] - mu2[t]) * (g2[t] * rsqrtf(v2[t] + BN_EPS)) + bt2[t];
  }
}

// ---------------- fused: 3NN + interpolate + concat + MLP, 512 threads ----------------
// B=16, n=4096, m=1024, C1=128, C2=256, Cin=384, H1=256, H2=128
// 64 points/block, 1024 blocks, 8 waves. LDS ~53 KB -> 3 blocks/CU (24 waves/CU).
// smem union layout:
//   nn3 phase : sd f32[64][49] @0 (12544) | si u16[64][49] @12544 (6272) | kxyz f4[1024] @18816 (16384)
//   mlp phase : xA 64x512B @0 (bf16 cols 0..256; later y-tile 64x256 bf16; later f32 out-tile)
//               xB 64x256B @35200 (bf16 cols 256..384, written during phase 0, NN-independent)
__global__ __launch_bounds__(512, 6)
void fp_fused_kernel(const float* __restrict__ unknown, const float* __restrict__ known,
                     const float* __restrict__ unknow_feats, const float* __restrict__ known_feats,
                     const unsigned short* __restrict__ W1b, const unsigned short* __restrict__ W2b,
                     const float* __restrict__ bias1, const float* __restrict__ bias2,
                     float* __restrict__ out) {
  __shared__ __align__(16) unsigned char smem[51584];
  __shared__ float w_s[192];
  __shared__ int   i_s[192];

  float* sd            = (float*)smem;
  unsigned short* si   = (unsigned short*)(smem + 12544);
  float4* kxyz         = (float4*)(smem + 18816);
  unsigned char* xA    = smem;
  unsigned char* xB    = smem + 35200;

  int bid = blockIdx.x;
  int swz = ((bid & 7) << 7) | (bid >> 3);           // XCD-contiguous remap, bijective for 1024
  int b   = swz >> 6;
  int i0  = (swz & 63) << 6;
  int tid = threadIdx.x;

  // ---- phase 0a: stage known xyz into float4-padded LDS ----
  {
    float* kf = (float*)kxyz;
    for (int t = tid; t < 3072; t += 512) {
      int r = t / 3, c = t - r * 3;
      kf[r * 4 + c] = known[b * 3072 + t];
    }
  }
  // ---- phase 0b: unknow_feats -> xB (cols 256..384), NN-independent ----
  {
    int pp = tid >> 5;
    int cq = tid & 31;
    const float4* uf = (const float4*)(unknow_feats + ((size_t)b * 4096 + i0) * 128);
    #pragma unroll
    for (int po = 0; po < 4; ++po) {
      int p = po * 16 + pp;
      float4 v = uf[p * 32 + cq];
      ushort4 h;
      h.x = f2bf(v.x); h.y = f2bf(v.y); h.z = f2bf(v.z); h.w = f2bf(v.w);
      int byte = p * 256 + cq * 8;
      byte ^= (p & 7) << 4;
      *(ushort4*)(xB + byte) = h;
    }
  }
  // ---- phase 0c: this thread's two query points ----
  int u  = tid & 31;                                  // point pair id
  int qc = tid >> 5;                                  // chunk 0..15
  const float* up = unknown + ((size_t)b * 4096 + i0 + 2 * u) * 3;
  float ax = up[0], ay = up[1], az = up[2];
  float bx = up[3], by = up[4], bz = up[5];
  __syncthreads();

  // ---- phase 1: top-3 over 64 candidates x 2 points (subtract form, fp32, strict <) ----
  {
    float a0 = 3e38f, a1 = 3e38f, a2 = 3e38f;
    float e0 = 3e38f, e1 = 3e38f, e2 = 3e38f;
    int aj0 = 0, aj1 = 0, aj2 = 0, ej0 = 0, ej1 = 0, ej2 = 0;
    int jb = qc << 6;
    #pragma unroll 4
    for (int jj = 0; jj < 64; ++jj) {
      int j = jb + jj;
      float4 k = kxyz[j];
      {
        float dx = ax - k.x, dy = ay - k.y, dz = az - k.z;
        float d = dx * dx + dy * dy + dz * dz;
        bool c0 = d < a0, c1 = d < a1, c2 = d < a2;
        aj2 = c1 ? aj1 : (c2 ? j : aj2);
        aj1 = c0 ? aj0 : (c1 ? j : aj1);
        aj0 = c0 ? j : aj0;
        float na2 = __builtin_amdgcn_fmed3f(a1, a2, d);
        float na1 = __builtin_amdgcn_fmed3f(a0, a1, d);
        a0 = fminf(a0, d); a1 = na1; a2 = na2;
      }
      {
        float dx = bx - k.x, dy = by - k.y, dz = bz - k.z;
        float d = dx * dx + dy * dy + dz * dz;
        bool c0 = d < e0, c1 = d < e1, c2 = d < e2;
        ej2 = c1 ? ej1 : (c2 ? j : ej2);
        ej1 = c0 ? ej0 : (c1 ? j : ej1);
        ej0 = c0 ? j : ej0;
        float na2 = __builtin_amdgcn_fmed3f(e1, e2, d);
        float na1 = __builtin_amdgcn_fmed3f(e0, e1, d);
        e0 = fminf(e0, d); e1 = na1; e2 = na2;
      }
    }
    int base = (2 * u) * 49 + qc * 3;
    sd[base] = a0; sd[base + 1] = a1; sd[base + 2] = a2;
    si[base] = (unsigned short)aj0; si[base + 1] = (unsigned short)aj1; si[base + 2] = (unsigned short)aj2;
    base += 49;
    sd[base] = e0; sd[base + 1] = e1; sd[base + 2] = e2;
    si[base] = (unsigned short)ej0; si[base + 1] = (unsigned short)ej1; si[base + 2] = (unsigned short)ej2;
  }
  __syncthreads();

  // ---- phase 2: merge 16 chunk-partials/point (chunk-ascending scan keeps low-index ties) ----
  if (tid < 64) {
    float m0 = 3e38f, m1 = 3e38f, m2 = 3e38f;
    int n0 = 0, n1 = 0, n2 = 0;
    int base = tid * 49;
    for (int e = 0; e < 48; ++e) {
      float d = sd[base + e]; int j = si[base + e];
      bool c0 = d < m0, c1 = d < m1, c2 = d < m2;
      n2 = c1 ? n1 : (c2 ? j : n2);
      n1 = c0 ? n0 : (c1 ? j : n1);
      n0 = c0 ? j : n0;
      float t2 = __builtin_amdgcn_fmed3f(m1, m2, d);
      float t1 = __builtin_amdgcn_fmed3f(m0, m1, d);
      m0 = fminf(m0, d); m1 = t1; m2 = t2;
    }
    float r0 = 1.0f / (m0 + 1e-10f);
    float r1 = 1.0f / (m1 + 1e-10f);
    float r2 = 1.0f / (m2 + 1e-10f);
    float rs = 1.0f / (r0 + r1 + r2);
    w_s[tid * 3 + 0] = r0 * rs; i_s[tid * 3 + 0] = n0;
    w_s[tid * 3 + 1] = r1 * rs; i_s[tid * 3 + 1] = n1;
    w_s[tid * 3 + 2] = r2 * rs; i_s[tid * 3 + 2] = n2;
  }
  __syncthreads();

  // ---- phase 3: interpolate -> xA cols [0,256) (overwrites nn3 scratch) ----
  {
    int pp = tid >> 6;                                // wave id
    int cq = tid & 63;
    const float4* kf = (const float4*)(known_feats + (size_t)b * 1024 * 256);
    #pragma unroll 2
    for (int po = 0; po < 8; ++po) {
      int p = po * 8 + pp;
      int ia = i_s[p * 3 + 0], ib = i_s[p * 3 + 1], ic = i_s[p * 3 + 2];
      float wa = w_s[p * 3 + 0], wb = w_s[p * 3 + 1], wc = w_s[p * 3 + 2];
      float4 va = kf[ia * 64 + cq];
      float4 vb = kf[ib * 64 + cq];
      float4 vc = kf[ic * 64 + cq];
      ushort4 h;
      h.x = f2bf(wa * va.x + wb * vb.x + wc * vc.x);
      h.y = f2bf(wa * va.y + wb * vb.y + wc * vc.y);
      h.z = f2bf(wa * va.z + wb * vb.z + wc * vc.z);
      h.w = f2bf(wa * va.w + wb * vb.w + wc * vc.w);
      int byte = p * 512 + cq * 8;
      byte ^= (p & 7) << 4;
      *(ushort4*)(xA + byte) = h;
    }
  }
  __syncthreads();

  // ---- phase 4: GEMM1 (64x384)x(384->256): wave q owns cols [32q, 32q+32) ----
  int l  = tid & 63;
  int q  = tid >> 6;
  int lr = l & 15;
  int lk = l >> 4;
  f32x4 acc[4][2];
  #pragma unroll
  for (int m = 0; m < 4; ++m)
    #pragma unroll
    for (int n = 0; n < 2; ++n) acc[m][n] = (f32x4){0.f, 0.f, 0.f, 0.f};

  __builtin_amdgcn_s_setprio(1);
  #pragma unroll
  for (int kk = 0; kk < 12; ++kk) {
    int kb = kk * 32 + lk * 8;                        // bf16 k index
    bf16x8 a[4];
    #pragma unroll
    for (int m = 0; m < 4; ++m) {
      int row = m * 16 + lr;
      if (kk < 8) {
        int byte = row * 512 + kb * 2;
        byte ^= (row & 7) << 4;
        a[m] = *(const bf16x8*)(xA + byte);
      } else {
        int byte = row * 256 + (kb - 256) * 2;
        byte ^= (row & 7) << 4;
        a[m] = *(const bf16x8*)(xB + byte);
      }
    }
    #pragma unroll
    for (int n = 0; n < 2; ++n) {
      int wr = q * 32 + n * 16 + lr;
      bf16x8 bb = *(const bf16x8*)(W1b + wr * 384 + kb);
      #pragma unroll
      for (int m = 0; m < 4; ++m)
        acc[m][n] = __builtin_amdgcn_mfma_f32_16x16x32_bf16(a[m], bb, acc[m][n], 0, 0, 0);
    }
  }
  __builtin_amdgcn_s_setprio(0);

  float bs1[2];
  #pragma unroll
  for (int n = 0; n < 2; ++n) bs1[n] = bias1[q * 32 + n * 16 + lr];

  __syncthreads();   // all xA/xB reads done; overwrite xA with y tile (64x256 bf16)
  #pragma unroll
  for (int m = 0; m < 4; ++m)
    #pragma unroll
    for (int n = 0; n < 2; ++n)
      #pragma unroll
      for (int i = 0; i < 4; ++i) {
        int r = m * 16 + lk * 4 + i;
        int c = q * 32 + n * 16 + lr;
        float val = fmaxf(acc[m][n][i] + bs1[n], 0.0f);
        int byte = r * 512 + c * 2;
        byte ^= (r & 7) << 4;
        *(unsigned short*)(xA + byte) = f2bf(val);
      }
  __syncthreads();

  // ---- phase 5: GEMM2 (64x256)x(256->128): wave q owns cols [16q, 16q+16) ----
  f32x4 acc2[4];
  #pragma unroll
  for (int m = 0; m < 4; ++m) acc2[m] = (f32x4){0.f, 0.f, 0.f, 0.f};

  __builtin_amdgcn_s_setprio(1);
  #pragma unroll
  for (int kk = 0; kk < 8; ++kk) {
    int kb = kk * 32 + lk * 8;
    bf16x8 a[4];
    #pragma unroll
    for (int m = 0; m < 4; ++m) {
      int row = m * 16 + lr;
      int byte = row * 512 + kb * 2;
      byte ^= (row & 7) << 4;
      a[m] = *(const bf16x8*)(xA + byte);
    }
    int wr = q * 16 + lr;
    bf16x8 bb = *(const bf16x8*)(W2b + wr * 256 + kb);
    #pragma unroll
    for (int m = 0; m < 4; ++m)
      acc2[m] = __builtin_amdgcn_mfma_f32_16x16x32_bf16(a[m], bb, acc2[m], 0, 0, 0);
  }
  __builtin_amdgcn_s_setprio(0);

  float bs2 = bias2[q * 16 + lr];

  // ---- epilogue: stage f32 out tile (stride 132), then coalesced float4 stores ----
  __syncthreads();   // all y-tile reads done
  float* ot = (float*)smem;
  #pragma unroll
  for (int m = 0; m < 4; ++m)
    #pragma unroll
    for (int i = 0; i < 4; ++i) {
      int r = m * 16 + lk * 4 + i;
      int c = q * 16 + lr;
      ot[r * 132 + c] = fmaxf(acc2[m][i] + bs2, 0.0f);
    }
  __syncthreads();
  {
    float4* out4 = (float4*)(out + ((size_t)b * 4096 + i0) * 128);
    #pragma unroll
    for (int t = tid; t < 2048; t += 512) {
      int pr = t >> 5;
      int c4 = t & 31;
      float4 v = *(const float4*)(ot + pr * 132 + c4 * 4);
      out4[pr * 32 + c4] = v;
    }
  }
}

extern "C" void kernel_launch(void* const* d_in, const int* in_sizes, int n_in,
                              void* d_out, int out_size, void* d_ws, size_t ws_size,
                              hipStream_t stream) {
  const float* unknown      = (const float*)d_in[0];
  const float* known        = (const float*)d_in[1];
  const float* unknow_feats = (const float*)d_in[2];
  const float* known_feats  = (const float*)d_in[3];
  const float* W1  = (const float*)d_in[4];
  const float* b1  = (const float*)d_in[5];
  const float* g1  = (const float*)d_in[6];
  const float* bt1 = (const float*)d_in[7];
  const float* mu1 = (const float*)d_in[8];
  const float* v1  = (const float*)d_in[9];
  const float* W2  = (const float*)d_in[10];
  const float* b2  = (const float*)d_in[11];
  const float* g2  = (const float*)d_in[12];
  const float* bt2 = (const float*)d_in[13];
  const float* mu2 = (const float*)d_in[14];
  const float* v2  = (const float*)d_in[15];

  unsigned short* W1b = (unsigned short*)d_ws;       // 98304 bf16
  unsigned short* W2b = W1b + 98304;                 // 32768 bf16
  float* bias1 = (float*)(W2b + 32768);              // 256 f32
  float* bias2 = bias1 + 256;                        // 128 f32

  prep_kernel<<<512, 256, 0, stream>>>(W1, b1, g1, bt1, mu1, v1,
                                       W2, b2, g2, bt2, mu2, v2,
                                       W1b, W2b, bias1, bias2);
  fp_fused_kernel<<<1024, 512, 0, stream>>>(unknown, known, unknow_feats, known_feats,
                                            W1b, W2b, bias1, bias2, (float*)d_out);
}

// Round 5
// 74.663 us; speedup vs baseline: 1.3784x; 1.0965x over previous
//
#include <hip/hip_runtime.h>
#include <stdint.h>

typedef float f32x4 __attribute__((ext_vector_type(4)));
typedef __bf16 bf16x8 __attribute__((ext_vector_type(8)));

#define BN_EPS 1e-5f

__device__ __forceinline__ unsigned short f2bf(float x) {
  union { float f; unsigned u; } v; v.f = x;
  unsigned r = v.u + 0x7fffu + ((v.u >> 16) & 1u);
  return (unsigned short)(r >> 16);
}

// ---------------- prep: fold BN into weights (bf16) + biases (fp32) ----------------
__global__ void prep_kernel(const float* __restrict__ W1, const float* __restrict__ b1,
                            const float* __restrict__ g1, const float* __restrict__ bt1,
                            const float* __restrict__ mu1, const float* __restrict__ v1,
                            const float* __restrict__ W2, const float* __restrict__ b2,
                            const float* __restrict__ g2, const float* __restrict__ bt2,
                            const float* __restrict__ mu2, const float* __restrict__ v2,
                            unsigned short* __restrict__ W1b, unsigned short* __restrict__ W2b,
                            float* __restrict__ bias1, float* __restrict__ bias2) {
  int tid = blockIdx.x * 256 + threadIdx.x;
  if (tid < 98304) {                       // W1: 256 x 384
    int o = tid / 384;
    float s = g1[o] * rsqrtf(v1[o] + BN_EPS);
    W1b[tid] = f2bf(W1[tid] * s);
    if (tid < 256) bias1[tid] = (b1[tid] - mu1[tid]) * (g1[tid] * rsqrtf(v1[tid] + BN_EPS)) + bt1[tid];
  } else if (tid < 98304 + 32768) {        // W2: 128 x 256
    int t = tid - 98304;
    int o = t / 256;
    float s = g2[o] * rsqrtf(v2[o] + BN_EPS);
    W2b[t] = f2bf(W2[t] * s);
    if (t < 128) bias2[t] = (b2[t] - mu2[t]) * (g2[t] * rsqrtf(v2[t] + BN_EPS)) + bt2[t];
  }
}

// ---------------- fused: 3NN + interpolate + concat + MLP, 512 threads ----------------
// 64 points/block, 1024 blocks, 8 waves. LDS 48 KB + w_s/i_s -> ~49.7 KB, 2 blocks/CU.
// smem union:
//   nn3 phase : sd f32[64][49] @0 (12544) | si u16[64][49] @12544 (6272) | kxyz f4[1024] @18816 (16384)
//   mlp phase : xA 64x512B @0 (bf16 cols 0..256; later y-tile; later f32 out-tile stride 132)
//               xB 64x256B @32768 (bf16 cols 256..384, staged during merge phase; kxyz dead by then)
__global__ __launch_bounds__(512, 4)
void fp_fused_kernel(const float* __restrict__ unknown, const float* __restrict__ known,
                     const float* __restrict__ unknow_feats, const float* __restrict__ known_feats,
                     const unsigned short* __restrict__ W1b, const unsigned short* __restrict__ W2b,
                     const float* __restrict__ bias1, const float* __restrict__ bias2,
                     float* __restrict__ out) {
  __shared__ __align__(16) unsigned char smem[49152];
  __shared__ float w_s[192];
  __shared__ int   i_s[192];

  float* sd          = (float*)smem;                  // [64][49]
  unsigned short* si = (unsigned short*)(smem + 12544);
  float4* kxyz       = (float4*)(smem + 18816);
  unsigned char* xA  = smem;
  unsigned char* xB  = smem + 32768;

  int bid = blockIdx.x;
  int swz = ((bid & 7) << 7) | (bid >> 3);            // XCD-contiguous remap, bijective for 1024
  int b   = swz >> 6;
  int i0  = (swz & 63) << 6;
  int tid = threadIdx.x;

  // ---- phase 0: stage known xyz (float4-padded) + this thread's two query points ----
  {
    float* kf = (float*)kxyz;
    for (int t = tid; t < 3072; t += 512) {
      int r = t / 3, c = t - r * 3;
      kf[r * 4 + c] = known[b * 3072 + t];
    }
  }
  int u  = tid & 31;                                  // point pair id
  int qc = tid >> 5;                                  // chunk 0..15
  const float* up = unknown + ((size_t)b * 4096 + i0 + 2 * u) * 3;
  float ax = up[0], ay = up[1], az = up[2];
  float bx = up[3], by = up[4], bz = up[5];
  __syncthreads();

  // ---- phase 1: exact fp32 top-3 over 64 candidates x 2 points (strict <) ----
  {
    float a0 = 3e38f, a1 = 3e38f, a2 = 3e38f;
    float e0 = 3e38f, e1 = 3e38f, e2 = 3e38f;
    int aj0 = 0, aj1 = 0, aj2 = 0, ej0 = 0, ej1 = 0, ej2 = 0;
    int jb = qc << 6;
    #pragma unroll 4
    for (int jj = 0; jj < 64; ++jj) {
      int j = jb + jj;
      float4 k = kxyz[j];
      {
        float dx = ax - k.x, dy = ay - k.y, dz = az - k.z;
        float d = dx * dx + dy * dy + dz * dz;
        bool c0 = d < a0, c1 = d < a1, c2 = d < a2;
        aj2 = c1 ? aj1 : (c2 ? j : aj2);
        aj1 = c0 ? aj0 : (c1 ? j : aj1);
        aj0 = c0 ? j : aj0;
        float na2 = __builtin_amdgcn_fmed3f(a1, a2, d);
        float na1 = __builtin_amdgcn_fmed3f(a0, a1, d);
        a0 = fminf(a0, d); a1 = na1; a2 = na2;
      }
      {
        float dx = bx - k.x, dy = by - k.y, dz = bz - k.z;
        float d = dx * dx + dy * dy + dz * dz;
        bool c0 = d < e0, c1 = d < e1, c2 = d < e2;
        ej2 = c1 ? ej1 : (c2 ? j : ej2);
        ej1 = c0 ? ej0 : (c1 ? j : ej1);
        ej0 = c0 ? j : ej0;
        float na2 = __builtin_amdgcn_fmed3f(e1, e2, d);
        float na1 = __builtin_amdgcn_fmed3f(e0, e1, d);
        e0 = fminf(e0, d); e1 = na1; e2 = na2;
      }
    }
    int base = (2 * u) * 49 + qc * 3;
    sd[base] = a0; sd[base + 1] = a1; sd[base + 2] = a2;
    si[base] = (unsigned short)aj0; si[base + 1] = (unsigned short)aj1; si[base + 2] = (unsigned short)aj2;
    base += 49;
    sd[base] = e0; sd[base + 1] = e1; sd[base + 2] = e2;
    si[base] = (unsigned short)ej0; si[base + 1] = (unsigned short)ej1; si[base + 2] = (unsigned short)ej2;
  }
  __syncthreads();

  // ---- phase 2: wave0 merges 48 partials/point; waves 1-7 stage xB (NN-independent) ----
  if (tid < 64) {
    float m0 = 3e38f, m1 = 3e38f, m2 = 3e38f;
    int n0 = 0, n1 = 0, n2 = 0;
    int base = tid * 49;
    for (int e = 0; e < 48; ++e) {
      float d = sd[base + e]; int j = si[base + e];
      bool c0 = d < m0, c1 = d < m1, c2 = d < m2;
      n2 = c1 ? n1 : (c2 ? j : n2);
      n1 = c0 ? n0 : (c1 ? j : n1);
      n0 = c0 ? j : n0;
      float t2 = __builtin_amdgcn_fmed3f(m1, m2, d);
      float t1 = __builtin_amdgcn_fmed3f(m0, m1, d);
      m0 = fminf(m0, d); m1 = t1; m2 = t2;
    }
    float r0 = 1.0f / (m0 + 1e-10f);
    float r1 = 1.0f / (m1 + 1e-10f);
    float r2 = 1.0f / (m2 + 1e-10f);
    float rs = 1.0f / (r0 + r1 + r2);
    w_s[tid * 3 + 0] = r0 * rs; i_s[tid * 3 + 0] = n0;
    w_s[tid * 3 + 1] = r1 * rs; i_s[tid * 3 + 1] = n1;
    w_s[tid * 3 + 2] = r2 * rs; i_s[tid * 3 + 2] = n2;
  } else {
    int t0 = tid - 64;                                 // 448 threads, 2048 ushort4 units
    const float4* uf = (const float4*)(unknow_feats + ((size_t)b * 4096 + i0) * 128);
    for (int t = t0; t < 2048; t += 448) {
      int p  = t >> 5;
      int cq = t & 31;
      float4 v = uf[p * 32 + cq];
      ushort4 h;
      h.x = f2bf(v.x); h.y = f2bf(v.y); h.z = f2bf(v.z); h.w = f2bf(v.w);
      int byte = p * 256 + cq * 8;
      byte ^= (p & 7) << 4;
      *(ushort4*)(xB + byte) = h;
    }
  }
  __syncthreads();

  // ---- phase 3: interpolate -> xA cols [0,256) (overwrites nn3 scratch) ----
  {
    int pp = tid >> 6;                                // wave id
    int cq = tid & 63;
    const float4* kf = (const float4*)(known_feats + (size_t)b * 1024 * 256);
    #pragma unroll 2
    for (int po = 0; po < 8; ++po) {
      int p = po * 8 + pp;
      int ia = i_s[p * 3 + 0], ib = i_s[p * 3 + 1], ic = i_s[p * 3 + 2];
      float wa = w_s[p * 3 + 0], wb = w_s[p * 3 + 1], wc = w_s[p * 3 + 2];
      float4 va = kf[ia * 64 + cq];
      float4 vb = kf[ib * 64 + cq];
      float4 vc = kf[ic * 64 + cq];
      ushort4 h;
      h.x = f2bf(wa * va.x + wb * vb.x + wc * vc.x);
      h.y = f2bf(wa * va.y + wb * vb.y + wc * vc.y);
      h.z = f2bf(wa * va.z + wb * vb.z + wc * vc.z);
      h.w = f2bf(wa * va.w + wb * vb.w + wc * vc.w);
      int byte = p * 512 + cq * 8;
      byte ^= (p & 7) << 4;
      *(ushort4*)(xA + byte) = h;
    }
  }
  __syncthreads();

  // ---- phase 4: GEMM1 (64x384)x(384->256): wave q owns cols [32q, 32q+32) ----
  int l  = tid & 63;
  int q  = tid >> 6;
  int lr = l & 15;
  int lk = l >> 4;
  f32x4 acc[4][2];
  #pragma unroll
  for (int m = 0; m < 4; ++m)
    #pragma unroll
    for (int n = 0; n < 2; ++n) acc[m][n] = (f32x4){0.f, 0.f, 0.f, 0.f};

  __builtin_amdgcn_s_setprio(1);
  #pragma unroll
  for (int kk = 0; kk < 12; ++kk) {
    int kb = kk * 32 + lk * 8;                        // bf16 k index
    bf16x8 a[4];
    #pragma unroll
    for (int m = 0; m < 4; ++m) {
      int row = m * 16 + lr;
      if (kk < 8) {
        int byte = row * 512 + kb * 2;
        byte ^= (row & 7) << 4;
        a[m] = *(const bf16x8*)(xA + byte);
      } else {
        int byte = row * 256 + (kb - 256) * 2;
        byte ^= (row & 7) << 4;
        a[m] = *(const bf16x8*)(xB + byte);
      }
    }
    #pragma unroll
    for (int n = 0; n < 2; ++n) {
      int wr = q * 32 + n * 16 + lr;
      bf16x8 bb = *(const bf16x8*)(W1b + wr * 384 + kb);
      #pragma unroll
      for (int m = 0; m < 4; ++m)
        acc[m][n] = __builtin_amdgcn_mfma_f32_16x16x32_bf16(a[m], bb, acc[m][n], 0, 0, 0);
    }
  }
  __builtin_amdgcn_s_setprio(0);

  float bs1[2];
  #pragma unroll
  for (int n = 0; n < 2; ++n) bs1[n] = bias1[q * 32 + n * 16 + lr];

  __syncthreads();   // all xA/xB reads done; overwrite xA with y tile (64x256 bf16)
  #pragma unroll
  for (int m = 0; m < 4; ++m)
    #pragma unroll
    for (int n = 0; n < 2; ++n)
      #pragma unroll
      for (int i = 0; i < 4; ++i) {
        int r = m * 16 + lk * 4 + i;
        int c = q * 32 + n * 16 + lr;
        float val = fmaxf(acc[m][n][i] + bs1[n], 0.0f);
        int byte = r * 512 + c * 2;
        byte ^= (r & 7) << 4;
        *(unsigned short*)(xA + byte) = f2bf(val);
      }
  __syncthreads();

  // ---- phase 5: GEMM2 (64x256)x(256->128): wave q owns cols [16q, 16q+16) ----
  f32x4 acc2[4];
  #pragma unroll
  for (int m = 0; m < 4; ++m) acc2[m] = (f32x4){0.f, 0.f, 0.f, 0.f};

  __builtin_amdgcn_s_setprio(1);
  #pragma unroll
  for (int kk = 0; kk < 8; ++kk) {
    int kb = kk * 32 + lk * 8;
    bf16x8 a[4];
    #pragma unroll
    for (int m = 0; m < 4; ++m) {
      int row = m * 16 + lr;
      int byte = row * 512 + kb * 2;
      byte ^= (row & 7) << 4;
      a[m] = *(const bf16x8*)(xA + byte);
    }
    int wr = q * 16 + lr;
    bf16x8 bb = *(const bf16x8*)(W2b + wr * 256 + kb);
    #pragma unroll
    for (int m = 0; m < 4; ++m)
      acc2[m] = __builtin_amdgcn_mfma_f32_16x16x32_bf16(a[m], bb, acc2[m], 0, 0, 0);
  }
  __builtin_amdgcn_s_setprio(0);

  float bs2 = bias2[q * 16 + lr];

  // ---- epilogue: stage f32 out tile (stride 132), then coalesced float4 stores ----
  __syncthreads();   // all y-tile reads done
  float* ot = (float*)smem;
  #pragma unroll
  for (int m = 0; m < 4; ++m)
    #pragma unroll
    for (int i = 0; i < 4; ++i) {
      int r = m * 16 + lk * 4 + i;
      int c = q * 16 + lr;
      ot[r * 132 + c] = fmaxf(acc2[m][i] + bs2, 0.0f);
    }
  __syncthreads();
  {
    float4* out4 = (float4*)(out + ((size_t)b * 4096 + i0) * 128);
    #pragma unroll
    for (int t = tid; t < 2048; t += 512) {
      int pr = t >> 5;
      int c4 = t & 31;
      float4 v = *(const float4*)(ot + pr * 132 + c4 * 4);
      out4[pr * 32 + c4] = v;
    }
  }
}

extern "C" void kernel_launch(void* const* d_in, const int* in_sizes, int n_in,
                              void* d_out, int out_size, void* d_ws, size_t ws_size,
                              hipStream_t stream) {
  const float* unknown      = (const float*)d_in[0];
  const float* known        = (const float*)d_in[1];
  const float* unknow_feats = (const float*)d_in[2];
  const float* known_feats  = (const float*)d_in[3];
  const float* W1  = (const float*)d_in[4];
  const float* b1  = (const float*)d_in[5];
  const float* g1  = (const float*)d_in[6];
  const float* bt1 = (const float*)d_in[7];
  const float* mu1 = (const float*)d_in[8];
  const float* v1  = (const float*)d_in[9];
  const float* W2  = (const float*)d_in[10];
  const float* b2  = (const float*)d_in[11];
  const float* g2  = (const float*)d_in[12];
  const float* bt2 = (const float*)d_in[13];
  const float* mu2 = (const float*)d_in[14];
  const float* v2  = (const float*)d_in[15];

  unsigned short* W1b = (unsigned short*)d_ws;       // 98304 bf16
  unsigned short* W2b = W1b + 98304;                 // 32768 bf16
  float* bias1 = (float*)(W2b + 32768);              // 256 f32
  float* bias2 = bias1 + 256;                        // 128 f32

  prep_kernel<<<512, 256, 0, stream>>>(W1, b1, g1, bt1, mu1, v1,
                                       W2, b2, g2, bt2, mu2, v2,
                                       W1b, W2b, bias1, bias2);
  fp_fused_kernel<<<1024, 512, 0, stream>>>(unknown, known, unknow_feats, known_feats,
                                            W1b, W2b, bias1, bias2, (float*)d_out);
}